// Round 7
// baseline (469.246 us; speedup 1.0000x reference)
//
#include <hip/hip_runtime.h>
#include <cstdint>

typedef __bf16 bf16;
typedef __bf16 bf16x4 __attribute__((ext_vector_type(4)));
typedef __bf16 bf16x8 __attribute__((ext_vector_type(8)));
typedef float floatx4 __attribute__((ext_vector_type(4)));

#define MFMA32(a, b, c) __builtin_amdgcn_mfma_f32_16x16x32_bf16((a), (b), (c), 0, 0, 0)
#define MFMA16(a, b, c) __builtin_amdgcn_mfma_f32_16x16x16bf16_1k((a), (b), (c), 0, 0, 0)

__device__ inline bf16x8 cvt8(const float* p) {
    float4 u = *(const float4*)p;
    float4 v = *(const float4*)(p + 4);
    bf16x8 r;
    r[0] = (bf16)u.x; r[1] = (bf16)u.y; r[2] = (bf16)u.z; r[3] = (bf16)u.w;
    r[4] = (bf16)v.x; r[5] = (bf16)v.y; r[6] = (bf16)v.z; r[7] = (bf16)v.w;
    return r;
}

// ---------------------------------------------------------------------------
// Kernel 1: transpose + fp32->bf16 convert the four 512x512 weight matrices.
// ---------------------------------------------------------------------------
__global__ __launch_bounds__(256) void k_transpose(
    const float* __restrict__ w0, const float* __restrict__ w1,
    const float* __restrict__ w2, const float* __restrict__ w3,
    bf16* __restrict__ o0, bf16* __restrict__ o1,
    bf16* __restrict__ o2, bf16* __restrict__ o3)
{
    __shared__ float t[32][33];
    const float* in;
    bf16* out;
    switch (blockIdx.z) {
        case 0: in = w0; out = o0; break;
        case 1: in = w1; out = o1; break;
        case 2: in = w2; out = o2; break;
        default: in = w3; out = o3; break;
    }
    const int tx = threadIdx.x & 31;
    const int ty = threadIdx.x >> 5;
    const int r0 = blockIdx.y * 32;
    const int c0 = blockIdx.x * 32;
    #pragma unroll
    for (int i = 0; i < 32; i += 8)
        t[ty + i][tx] = in[(size_t)(r0 + ty + i) * 512 + c0 + tx];
    __syncthreads();
    #pragma unroll
    for (int i = 0; i < 32; i += 8)
        out[(size_t)(c0 + ty + i) * 512 + r0 + tx] = (bf16)t[tx][ty + i];
}

// ---------------------------------------------------------------------------
// Kernel 1b: X fp32 -> bf16 into d_out scratch (consumed by k_qkv).
// ---------------------------------------------------------------------------
__global__ __launch_bounds__(256) void k_cvtx(
    const float* __restrict__ X, bf16* __restrict__ Xb)
{
    const size_t idx = ((size_t)blockIdx.x * 256 + threadIdx.x) * 8;
    *(bf16x8*)(Xb + idx) = cvt8(X + idx);
}

// ---------------------------------------------------------------------------
// Kernel 2: fused QKV projection from bf16 X. Q pre-scaled by
// 0.125*log2(e) so attention uses exp2 directly. V stored transposed
// Vt[bh][d][s] (packed 8B stores).
// ---------------------------------------------------------------------------
__global__ __launch_bounds__(256) void k_qkv(
    const bf16* __restrict__ Xb,
    const bf16* __restrict__ Wtq, const bf16* __restrict__ Wtk, const bf16* __restrict__ Wtv,
    const float* __restrict__ bq, const float* __restrict__ bk, const float* __restrict__ bv,
    bf16* __restrict__ Qs, bf16* __restrict__ Ks, bf16* __restrict__ Vt)
{
    const int tid  = threadIdx.x;
    const int w    = tid >> 6;
    const int lane = tid & 63;
    const int col  = lane & 15;
    const int quad = lane >> 4;
    const int m0 = blockIdx.x * 64 + w * 16;
    const int n0 = blockIdx.y * 64;

    const floatx4 zf = {0.f, 0.f, 0.f, 0.f};
    floatx4 acc[3][4];
    #pragma unroll
    for (int m = 0; m < 3; ++m)
        #pragma unroll
        for (int t = 0; t < 4; ++t) acc[m][t] = zf;

    const bf16* xp = Xb + (size_t)(m0 + col) * 512 + quad * 8;

    for (int k0 = 0; k0 < 512; k0 += 32) {
        bf16x8 a = *(const bf16x8*)(xp + k0);
        #pragma unroll
        for (int t = 0; t < 4; ++t) {
            const size_t woff = (size_t)(n0 + 16 * t + col) * 512 + k0 + quad * 8;
            acc[0][t] = MFMA32(a, *(const bf16x8*)(Wtq + woff), acc[0][t]);
            acc[1][t] = MFMA32(a, *(const bf16x8*)(Wtk + woff), acc[1][t]);
            acc[2][t] = MFMA32(a, *(const bf16x8*)(Wtv + woff), acc[2][t]);
        }
    }

    const float qsc = 0.125f * 1.44269504088896f;   // fold log2(e) into Q
    #pragma unroll
    for (int t = 0; t < 4; ++t) {
        const int n = n0 + 16 * t + col;
        const int h = n >> 6;
        const int d = n & 63;
        const float bqv = bq[n];
        const float bkv = bk[n];
        const float bvv = bv[n];
        #pragma unroll
        for (int r = 0; r < 4; ++r) {
            const int m = m0 + quad * 4 + r;
            const int b = m >> 12;
            const int s = m & 4095;
            const size_t off = (((size_t)b * 8 + h) * 4096 + s) * 64 + d;
            Qs[off] = (bf16)((acc[0][t][r] + bqv) * qsc);
            Ks[off] = (bf16)(acc[1][t][r] + bkv);
        }
        {   // packed Vt store: 4 consecutive s at (bh, d)
            const int m = m0 + quad * 4;
            const int b = m >> 12;
            const int s = m & 4095;
            union { bf16 e[4]; uint2 u; } pk;
            #pragma unroll
            for (int r = 0; r < 4; ++r) pk.e[r] = (bf16)(acc[2][t][r] + bvv);
            *(uint2*)(Vt + (((size_t)b * 8 + h) * 64 + d) * 4096 + s) = pk.u;
        }
    }
}

// ---------------------------------------------------------------------------
// Kernel 3: attention, transposed-score formulation. S^T = K*Q^T (same
// register fragments as QK^T, swapped MFMA operands) gives C-layout with 4
// KEYS per lane = exactly the B-fragment of v_mfma_f32_16x16x16_bf16. So
// exp(S^T) feeds O^T = V^T * P^T fully in-lane: NO P LDS round-trip, no
// shuffles. 128-thr blocks (2 waves), 64 q/wave, BK=32 keys staged in
// double-buffered swizzled LDS (K rows + Vt rows). One barrier/iter.
// Streaming softmax (scores bounded, exp2-based), l reduced once at end.
// ---------------------------------------------------------------------------
__global__ __launch_bounds__(128) void k_attn(
    const bf16* __restrict__ Qs, const bf16* __restrict__ Ks, const bf16* __restrict__ Vt,
    bf16* __restrict__ attb)
{
    __shared__ uint4 Klds[2][256];   // [key 0..31][chunk d/8 ^ (key&7)]
    __shared__ uint2 Vlds[2][512];   // [d 0..63][unit key/4 ^ (d&7)]

    const int tid  = threadIdx.x;
    const int w    = tid >> 6;
    const int lane = tid & 63;
    const int col  = lane & 15;
    const int quad = lane >> 4;
    const int i    = blockIdx.x;
    const int bh   = ((i & 7) << 1) | ((i >> 3) & 1);   // 2 heads per XCD
    const int q0   = (i >> 4) * 128 + w * 64;

    const bf16* Qb = Qs + (size_t)bh * 262144;
    const bf16* Kb = Ks + (size_t)bh * 262144;
    const bf16* Vb = Vt + (size_t)bh * 262144;

    // staging source geometry (tile-invariant)
    const int rK = tid >> 3;              // K row (key) 0..15 (+16 rep)
    const int cK = tid & 7;               // 16B chunk
    const int dV = tid >> 2;              // V d 0..31 (+32 rep)
    const int uV = tid & 3;               // 16B unit-pair index

    // Q fragments: 4 row-sets x 2 dim-halves, resident all kernel
    bf16x8 aq[4][2];
    #pragma unroll
    for (int s = 0; s < 4; ++s)
        #pragma unroll
        for (int c = 0; c < 2; ++c)
            aq[s][c] = *(const bf16x8*)(Qb + (size_t)(q0 + 16 * s + col) * 64 + 32 * c + quad * 8);

    const floatx4 zf = {0.f, 0.f, 0.f, 0.f};
    floatx4 o[4][4];                       // [s][d-tile], O^T C-layout
    float lsum[4] = {0.f, 0.f, 0.f, 0.f};
    #pragma unroll
    for (int s = 0; s < 4; ++s)
        #pragma unroll
        for (int dt = 0; dt < 4; ++dt) o[s][dt] = zf;

    // prologue: stage tile 0 into buffer 0
    #pragma unroll
    for (int rep = 0; rep < 2; ++rep) {
        const int row = rK + 16 * rep;
        Klds[0][row * 8 + (cK ^ (row & 7))] = *(const uint4*)(Kb + (size_t)row * 64 + cK * 8);
        const int d = dV + 32 * rep;
        union { uint4 q; uint2 h[2]; } vv;
        vv.q = *(const uint4*)(Vb + (size_t)d * 4096 + uV * 8);
        Vlds[0][d * 8 + ((2 * uV) ^ (d & 7))]     = vv.h[0];
        Vlds[0][d * 8 + ((2 * uV + 1) ^ (d & 7))] = vv.h[1];
    }
    __syncthreads();

    int buf = 0;
    for (int kt = 0; kt < 4096; kt += 32) {
        // prefetch next tile into registers (consumed at loop end)
        const int kn = (kt + 32) & 4095;
        uint4 kpre[2], vpre[2];
        #pragma unroll
        for (int rep = 0; rep < 2; ++rep) {
            kpre[rep] = *(const uint4*)(Kb + (size_t)(kn + rK + 16 * rep) * 64 + cK * 8);
            vpre[rep] = *(const uint4*)(Vb + (size_t)(dV + 32 * rep) * 4096 + kn + uV * 8);
        }

        // fragments from LDS
        const uint4* Kl = Klds[buf];
        const uint2* Vl = Vlds[buf];
        bf16x8 kf[2][2];
        #pragma unroll
        for (int t = 0; t < 2; ++t)
            #pragma unroll
            for (int c = 0; c < 2; ++c) {
                union { uint4 u; bf16x8 v; } cv;
                cv.u = Kl[(16 * t + col) * 8 + ((4 * c + quad) ^ (col & 7))];
                kf[t][c] = cv.v;
            }
        bf16x4 vfrag[4][2];
        #pragma unroll
        for (int dt = 0; dt < 4; ++dt)
            #pragma unroll
            for (int t = 0; t < 2; ++t) {
                union { uint2 u; bf16x4 v; } cv;
                cv.u = Vl[(16 * dt + col) * 8 + ((4 * t + quad) ^ (col & 7))];
                vfrag[dt][t] = cv.v;
            }

        // S^T = K*Q^T -> exp2 -> P^T B-fragments in-lane -> O^T += V^T*P^T
        #pragma unroll
        for (int s = 0; s < 4; ++s) {
            bf16x4 pw[2];
            #pragma unroll
            for (int t = 0; t < 2; ++t) {
                floatx4 sc = MFMA32(kf[t][1], aq[s][1], MFMA32(kf[t][0], aq[s][0], zf));
                const float p0 = exp2f(sc[0]);
                const float p1 = exp2f(sc[1]);
                const float p2 = exp2f(sc[2]);
                const float p3 = exp2f(sc[3]);
                lsum[s] += (p0 + p1) + (p2 + p3);
                union { bf16 e[4]; bf16x4 v; } pk;
                pk.e[0] = (bf16)p0; pk.e[1] = (bf16)p1;
                pk.e[2] = (bf16)p2; pk.e[3] = (bf16)p3;
                pw[t] = pk.v;
            }
            #pragma unroll
            for (int dt = 0; dt < 4; ++dt) {
                o[s][dt] = MFMA16(vfrag[dt][0], pw[0], o[s][dt]);
                o[s][dt] = MFMA16(vfrag[dt][1], pw[1], o[s][dt]);
            }
        }

        // store prefetched tile, flip buffers
        #pragma unroll
        for (int rep = 0; rep < 2; ++rep) {
            const int row = rK + 16 * rep;
            Klds[buf ^ 1][row * 8 + (cK ^ (row & 7))] = kpre[rep];
            const int d = dV + 32 * rep;
            union { uint4 q; uint2 h[2]; } vv;
            vv.q = vpre[rep];
            Vlds[buf ^ 1][d * 8 + ((2 * uV) ^ (d & 7))]     = vv.h[0];
            Vlds[buf ^ 1][d * 8 + ((2 * uV + 1) ^ (d & 7))] = vv.h[1];
        }
        __syncthreads();
        buf ^= 1;
    }

    // l: reduce across quads (keys were split quad*4+r within lanes)
    float inv[4];
    #pragma unroll
    for (int s = 0; s < 4; ++s) {
        float v = lsum[s];
        v += __shfl_xor(v, 16, 64);
        v += __shfl_xor(v, 32, 64);
        inv[s] = 1.0f / v;
    }

    const int b = bh >> 3;
    const int h = bh & 7;
    #pragma unroll
    for (int s = 0; s < 4; ++s)
        #pragma unroll
        for (int dt = 0; dt < 4; ++dt) {
            union { bf16 e[4]; uint2 u; } pk;
            #pragma unroll
            for (int r = 0; r < 4; ++r) pk.e[r] = (bf16)(o[s][dt][r] * inv[s]);
            const size_t row = (size_t)b * 4096 + q0 + 16 * s + col;
            *(uint2*)(attb + row * 1024 + h * 64 + 16 * dt + 4 * quad) = pk.u;
        }
}

// ---------------------------------------------------------------------------
// Kernel 4: in-place output projection, 16 rows/block (512 blocks).
// ---------------------------------------------------------------------------
__global__ __launch_bounds__(256) void k_oproj(
    const bf16* __restrict__ Wto, const float* __restrict__ bo, void* dout)
{
    const bf16*  attb = (const bf16*)dout;
    float*       out  = (float*)dout;
    const int tid  = threadIdx.x;
    const int w    = tid >> 6;
    const int lane = tid & 63;
    const int col  = lane & 15;
    const int quad = lane >> 4;
    const int m0 = blockIdx.x * 16;

    bf16x8 aA[16];
    #pragma unroll
    for (int ks = 0; ks < 16; ++ks)
        aA[ks] = *(const bf16x8*)(attb + (size_t)(m0 + col) * 1024 + ks * 32 + quad * 8);

    __syncthreads();   // all A loads complete before any fp32 store

    const floatx4 zf = {0.f, 0.f, 0.f, 0.f};
    #pragma unroll
    for (int tt = 0; tt < 8; ++tt) {
        const int t = w * 8 + tt;
        floatx4 acc = zf;
        #pragma unroll
        for (int ks = 0; ks < 16; ++ks) {
            const size_t woff = (size_t)(t * 16 + col) * 512 + ks * 32 + quad * 8;
            acc = MFMA32(aA[ks], *(const bf16x8*)(Wto + woff), acc);
        }
        const int n = t * 16 + col;
        const float bov = bo[n];
        #pragma unroll
        for (int r = 0; r < 4; ++r)
            out[(size_t)(m0 + quad * 4 + r) * 512 + n] = acc[r] + bov;
    }
}

// ---------------------------------------------------------------------------
extern "C" void kernel_launch(void* const* d_in, const int* in_sizes, int n_in,
                              void* d_out, int out_size, void* d_ws, size_t ws_size,
                              hipStream_t stream)
{
    const float* X  = (const float*)d_in[0];
    const float* Wq = (const float*)d_in[1];
    const float* bq = (const float*)d_in[2];
    const float* Wk = (const float*)d_in[3];
    const float* bk = (const float*)d_in[4];
    const float* Wv = (const float*)d_in[5];
    const float* bv = (const float*)d_in[6];
    const float* Wo = (const float*)d_in[7];
    const float* bo = (const float*)d_in[8];

    // workspace (bf16 elements): 4 weights + Q + K + Vt = 27.2 MB
    bf16* Wtq = (bf16*)d_ws;
    bf16* Wtk = Wtq + 512 * 512;
    bf16* Wtv = Wtk + 512 * 512;
    bf16* Wto = Wtv + 512 * 512;
    bf16* Qs  = Wto + 512 * 512;               // [16][4096][64]
    bf16* Ks  = Qs + (size_t)16 * 4096 * 64;   // [16][4096][64]
    bf16* Vt  = Ks + (size_t)16 * 4096 * 64;   // [16][64][4096]

    bf16* Xb  = (bf16*)d_out;                  // scratch: consumed by k_qkv
                                               // before k_attn overwrites d_out

    k_transpose<<<dim3(16, 16, 4), 256, 0, stream>>>(Wq, Wk, Wv, Wo, Wtq, Wtk, Wtv, Wto);
    k_cvtx<<<2048, 256, 0, stream>>>(X, Xb);
    k_qkv<<<dim3(128, 8), 256, 0, stream>>>(Xb, Wtq, Wtk, Wtv, bq, bk, bv, Qs, Ks, Vt);
    k_attn<<<512, 128, 0, stream>>>(Qs, Ks, Vt, (bf16*)d_out);
    k_oproj<<<dim3(512), 256, 0, stream>>>(Wto, bo, d_out);
}

// Round 8
// 251.205 us; speedup vs baseline: 1.8680x; 1.8680x over previous
//
#include <hip/hip_runtime.h>
#include <cstdint>

typedef __bf16 bf16;
typedef __bf16 bf16x8 __attribute__((ext_vector_type(8)));
typedef float floatx4 __attribute__((ext_vector_type(4)));

#define MFMA32(a, b, c) __builtin_amdgcn_mfma_f32_16x16x32_bf16((a), (b), (c), 0, 0, 0)

__device__ inline bf16x8 cvt8(const float* p) {
    float4 u = *(const float4*)p;
    float4 v = *(const float4*)(p + 4);
    bf16x8 r;
    r[0] = (bf16)u.x; r[1] = (bf16)u.y; r[2] = (bf16)u.z; r[3] = (bf16)u.w;
    r[4] = (bf16)v.x; r[5] = (bf16)v.y; r[6] = (bf16)v.z; r[7] = (bf16)v.w;
    return r;
}

// ---------------------------------------------------------------------------
// Kernel 1: transpose + fp32->bf16 convert the four 512x512 weight matrices.
// ---------------------------------------------------------------------------
__global__ __launch_bounds__(256) void k_transpose(
    const float* __restrict__ w0, const float* __restrict__ w1,
    const float* __restrict__ w2, const float* __restrict__ w3,
    bf16* __restrict__ o0, bf16* __restrict__ o1,
    bf16* __restrict__ o2, bf16* __restrict__ o3)
{
    __shared__ float t[32][33];
    const float* in;
    bf16* out;
    switch (blockIdx.z) {
        case 0: in = w0; out = o0; break;
        case 1: in = w1; out = o1; break;
        case 2: in = w2; out = o2; break;
        default: in = w3; out = o3; break;
    }
    const int tx = threadIdx.x & 31;
    const int ty = threadIdx.x >> 5;
    const int r0 = blockIdx.y * 32;
    const int c0 = blockIdx.x * 32;
    #pragma unroll
    for (int i = 0; i < 32; i += 8)
        t[ty + i][tx] = in[(size_t)(r0 + ty + i) * 512 + c0 + tx];
    __syncthreads();
    #pragma unroll
    for (int i = 0; i < 32; i += 8)
        out[(size_t)(c0 + ty + i) * 512 + r0 + tx] = (bf16)t[tx][ty + i];
}

// ---------------------------------------------------------------------------
// Kernel 1b: X fp32 -> bf16 into d_out scratch (consumed by k_qkv; d_out is
// only written again by k_oproj at the very end).
// ---------------------------------------------------------------------------
__global__ __launch_bounds__(256) void k_cvtx(
    const float* __restrict__ X, bf16* __restrict__ Xb)
{
    const size_t idx = ((size_t)blockIdx.x * 256 + threadIdx.x) * 8;
    *(bf16x8*)(Xb + idx) = cvt8(X + idx);
}

// ---------------------------------------------------------------------------
// Kernel 2: QKV as one m97-style GEMM. C[8192][1536] = Xb @ Wcat^T where
// Wcat = [Wq^T;Wk^T;Wv^T] rows (contiguous in ws). 128x128 tile, BK=32,
// double-buffered LDS (reg-prefetch staging), 8 ds_read_b128 + 16 MFMA per
// wave-step. Epilogue per block-uniform `which`: Q (bias, *0.125*log2e,
// head-split), K (bias, head-split), V (bias, transposed Vt[bh][d][s]).
// ---------------------------------------------------------------------------
__global__ __launch_bounds__(256) void k_qkv(
    const bf16* __restrict__ Xb, const bf16* __restrict__ Wcat,
    const float* __restrict__ bq, const float* __restrict__ bk, const float* __restrict__ bv,
    bf16* __restrict__ Qs, bf16* __restrict__ Ks, bf16* __restrict__ Vt)
{
    __shared__ uint4 Al[2][512];   // 128 rows x 4 chunks (16B) = 8KB / buf
    __shared__ uint4 Bl[2][512];

    const int tid  = threadIdx.x;
    const int w    = tid >> 6;
    const int lane = tid & 63;
    const int col  = lane & 15;
    const int quad = lane >> 4;
    const int m0 = blockIdx.x * 128;
    const int n0 = blockIdx.y * 128;

    // staging geometry: chunk c = tid (+256); row = c>>2, phys chunk = c&3
    const bf16* gA0 = Xb   + (size_t)(m0 + (tid >> 2)) * 512 + (tid & 3) * 8;
    const bf16* gA1 = gA0 + 64 * 512;
    const bf16* gB0 = Wcat + (size_t)(n0 + (tid >> 2)) * 512 + (tid & 3) * 8;
    const bf16* gB1 = gB0 + 64 * 512;

    const floatx4 zf = {0.f, 0.f, 0.f, 0.f};
    floatx4 acc[4][4];
    #pragma unroll
    for (int a = 0; a < 4; ++a)
        #pragma unroll
        for (int b = 0; b < 4; ++b) acc[a][b] = zf;

    // prologue: stage k0=0
    Al[0][tid]       = *(const uint4*)gA0;
    Al[0][tid + 256] = *(const uint4*)gA1;
    Bl[0][tid]       = *(const uint4*)gB0;
    Bl[0][tid + 256] = *(const uint4*)gB1;
    __syncthreads();

    const int mb = (w & 1) * 64;    // wave quadrant
    const int nb = (w >> 1) * 64;

    int buf = 0;
    for (int kk = 0; kk < 16; ++kk) {
        const int kn = ((kk + 1) & 15) * 32;   // wraparound prefetch
        const uint4 pa0 = *(const uint4*)(gA0 + kn);
        const uint4 pa1 = *(const uint4*)(gA1 + kn);
        const uint4 pb0 = *(const uint4*)(gB0 + kn);
        const uint4 pb1 = *(const uint4*)(gB1 + kn);

        const uint4* A4 = Al[buf];
        const uint4* B4 = Bl[buf];
        bf16x8 af[4], bfr[4];
        #pragma unroll
        for (int t = 0; t < 4; ++t) {
            union { uint4 u; bf16x8 v; } ca, cb;
            ca.u = A4[(mb + 16 * t + col) * 4 + quad];
            cb.u = B4[(nb + 16 * t + col) * 4 + quad];
            af[t] = ca.v;
            bfr[t] = cb.v;
        }
        #pragma unroll
        for (int tm = 0; tm < 4; ++tm)
            #pragma unroll
            for (int tn = 0; tn < 4; ++tn)
                acc[tm][tn] = MFMA32(af[tm], bfr[tn], acc[tm][tn]);

        Al[buf ^ 1][tid]       = pa0;
        Al[buf ^ 1][tid + 256] = pa1;
        Bl[buf ^ 1][tid]       = pb0;
        Bl[buf ^ 1][tid + 256] = pb1;
        __syncthreads();
        buf ^= 1;
    }

    // epilogue
    const int which = blockIdx.y >> 2;                    // 0=Q 1=K 2=V
    const int nbase = (blockIdx.y & 3) * 128 + nb;        // 0..511
    const int mbase = m0 + mb;
    const float qsc = 0.125f * 1.44269504088896f;         // fold log2(e)

    if (which == 0) {
        #pragma unroll
        for (int tn = 0; tn < 4; ++tn) {
            const int n = nbase + 16 * tn + col;
            const int h = n >> 6, d = n & 63;
            const float bb = bq[n];
            #pragma unroll
            for (int tm = 0; tm < 4; ++tm)
                #pragma unroll
                for (int r = 0; r < 4; ++r) {
                    const int m = mbase + 16 * tm + quad * 4 + r;
                    const int b = m >> 12, s = m & 4095;
                    Qs[(((size_t)b * 8 + h) * 4096 + s) * 64 + d] =
                        (bf16)((acc[tm][tn][r] + bb) * qsc);
                }
        }
    } else if (which == 1) {
        #pragma unroll
        for (int tn = 0; tn < 4; ++tn) {
            const int n = nbase + 16 * tn + col;
            const int h = n >> 6, d = n & 63;
            const float bb = bk[n];
            #pragma unroll
            for (int tm = 0; tm < 4; ++tm)
                #pragma unroll
                for (int r = 0; r < 4; ++r) {
                    const int m = mbase + 16 * tm + quad * 4 + r;
                    const int b = m >> 12, s = m & 4095;
                    Ks[(((size_t)b * 8 + h) * 4096 + s) * 64 + d] =
                        (bf16)(acc[tm][tn][r] + bb);
                }
        }
    } else {
        #pragma unroll
        for (int tn = 0; tn < 4; ++tn) {
            const int n = nbase + 16 * tn + col;
            const int h = n >> 6, d = n & 63;
            const float bb = bv[n];
            #pragma unroll
            for (int tm = 0; tm < 4; ++tm) {
                const int m = mbase + 16 * tm + quad * 4;
                const int b = m >> 12, s = m & 4095;
                union { bf16 e[4]; uint2 u; } pk;
                #pragma unroll
                for (int r = 0; r < 4; ++r) pk.e[r] = (bf16)(acc[tm][tn][r] + bb);
                *(uint2*)(Vt + (((size_t)b * 8 + h) * 64 + d) * 4096 + s) = pk.u;
            }
        }
    }
}

// ---------------------------------------------------------------------------
// Kernel 3: attention (R6 structure, reverted). 512 blocks (2/CU), 128
// q-rows/block, 32/wave. K/V tiles staged in double-buffered swizzled LDS
// shared by all 4 waves; P via wave-private uint32 LDS; one barrier/iter.
// Streaming softmax with exp2 (Q pre-scaled by 0.125*log2e).
// ---------------------------------------------------------------------------
__global__ __launch_bounds__(256, 2) void k_attn(
    const bf16* __restrict__ Qs, const bf16* __restrict__ Ks, const bf16* __restrict__ Vt,
    bf16* __restrict__ att)
{
    __shared__ uint4 Klds[2][256];        // 32 keys x 64 d, chunk c^(row&7)
    __shared__ uint4 Vlds[2][256];        // 64 d x 32 keys, pair swizzle
    __shared__ uint32_t Pt_all[4 * 32 * 17];

    const int tid  = threadIdx.x;
    const int w    = tid >> 6;
    const int lane = tid & 63;
    const int col  = lane & 15;
    const int quad = lane >> 4;
    const int i    = blockIdx.x;
    const int bh   = ((i & 7) << 1) | ((i >> 3) & 1);   // 2 heads per XCD
    const int q0   = (i >> 4) * 128 + w * 32;

    const bf16* Qb = Qs + (size_t)bh * 262144;
    const bf16* Kb = Ks + (size_t)bh * 262144;
    const bf16* Vb = Vt + (size_t)bh * 262144;
    uint32_t* Pt = Pt_all + w * 32 * 17;

    const int rK  = tid >> 3;
    const int lcK = (tid & 7) ^ (rK & 7);
    const bf16* gK = Kb + (size_t)rK * 64 + lcK * 8;
    const int pV  = tid >> 3;
    const int ccV = (tid & 7) ^ (pV & 7);
    const int dV  = 2 * pV + (ccV >> 2);
    const int cV  = ccV & 3;
    const bf16* gV = Vb + (size_t)dV * 4096 + cV * 8;

    bf16x8 aq[2][2];
    #pragma unroll
    for (int s = 0; s < 2; ++s)
        #pragma unroll
        for (int c = 0; c < 2; ++c)
            aq[s][c] = *(const bf16x8*)(Qb + (size_t)(q0 + 16 * s + col) * 64 + 32 * c + quad * 8);

    const floatx4 zf = {0.f, 0.f, 0.f, 0.f};
    floatx4 o[2][4];
    float l[2][4];
    #pragma unroll
    for (int s = 0; s < 2; ++s) {
        #pragma unroll
        for (int t = 0; t < 4; ++t) o[s][t] = zf;
        #pragma unroll
        for (int r = 0; r < 4; ++r) l[s][r] = 0.f;
    }

    const uint32_t sel = (col & 1) ? 0x07060302u : 0x05040100u;

    Klds[0][tid] = *(const uint4*)gK;
    Vlds[0][tid] = *(const uint4*)gV;
    __syncthreads();

    int buf = 0;
    for (int kt = 0; kt < 4096; kt += 32) {
        const int kn = (kt + 32) & 4095;
        const uint4 kreg = *(const uint4*)(gK + (size_t)kn * 64);
        const uint4 vreg = *(const uint4*)(gV + kn);

        const uint4* Kl = Klds[buf];
        const uint4* Vl = Vlds[buf];
        bf16x8 kf[2][2], vf[4];
        #pragma unroll
        for (int t = 0; t < 2; ++t)
            #pragma unroll
            for (int h = 0; h < 2; ++h) {
                union { uint4 u; bf16x8 v; } cv;
                cv.u = Kl[(16 * t + col) * 8 + ((quad + 4 * h) ^ (col & 7))];
                kf[t][h] = cv.v;
            }
        #pragma unroll
        for (int t = 0; t < 4; ++t) {
            union { uint4 u; bf16x8 v; } cv;
            cv.u = Vl[(8 * t + (col >> 1)) * 8 + ((((col & 1) * 4) + quad) ^ ((col >> 1) & 7))];
            vf[t] = cv.v;
        }

        #pragma unroll
        for (int s = 0; s < 2; ++s) {
            #pragma unroll
            for (int t = 0; t < 2; ++t) {
                floatx4 sc = MFMA32(aq[s][1], kf[t][1], MFMA32(aq[s][0], kf[t][0], zf));
                float p0 = exp2f(sc[0]);
                float p1 = exp2f(sc[1]);
                float p2 = exp2f(sc[2]);
                float p3 = exp2f(sc[3]);
                l[s][0] += p0; l[s][1] += p1; l[s][2] += p2; l[s][3] += p3;
                union { bf16 e[4]; uint32_t u[2]; } pk;
                pk.e[0] = (bf16)p0; pk.e[1] = (bf16)p1;
                pk.e[2] = (bf16)p2; pk.e[3] = (bf16)p3;
                uint32_t* dst = Pt + (16 * t + col) * 17 + 8 * s + 2 * quad;
                dst[0] = pk.u[0];
                dst[1] = pk.u[1];
            }
        }
        #pragma unroll
        for (int s = 0; s < 2; ++s) {
            uint32_t wd[8];
            #pragma unroll
            for (int j = 0; j < 8; ++j)
                wd[j] = Pt[(quad * 8 + j) * 17 + 8 * s + (col >> 1)];
            union { uint32_t u[4]; bf16x8 v; } ap;
            #pragma unroll
            for (int ii = 0; ii < 4; ++ii)
                ap.u[ii] = __builtin_amdgcn_perm(wd[2 * ii + 1], wd[2 * ii], sel);
            #pragma unroll
            for (int t = 0; t < 4; ++t)
                o[s][t] = MFMA32(ap.v, vf[t], o[s][t]);
        }

        Klds[buf ^ 1][tid] = kreg;
        Vlds[buf ^ 1][tid] = vreg;
        __syncthreads();
        buf ^= 1;
    }

    #pragma unroll
    for (int s = 0; s < 2; ++s)
        #pragma unroll
        for (int r = 0; r < 4; ++r) {
            float v = l[s][r];
            v += __shfl_xor(v, 1, 64);
            v += __shfl_xor(v, 2, 64);
            v += __shfl_xor(v, 4, 64);
            v += __shfl_xor(v, 8, 64);
            l[s][r] = 1.0f / v;
        }

    const int b = bh >> 3;
    const int h = bh & 7;
    #pragma unroll
    for (int s = 0; s < 2; ++s)
        #pragma unroll
        for (int t = 0; t < 4; ++t)
            #pragma unroll
            for (int r = 0; r < 4; ++r) {
                const size_t row = (size_t)b * 4096 + q0 + 16 * s + 4 * quad + r;
                att[row * 512 + h * 64 + 16 * t + col] = (bf16)(o[s][t][r] * l[s][r]);
            }
}

// ---------------------------------------------------------------------------
// Kernel 4: output projection as m97-style GEMM. out[8192][512] fp32 =
// att @ Wto^T + bo. Same core as k_qkv; grid (64,4); no aliasing.
// ---------------------------------------------------------------------------
__global__ __launch_bounds__(256) void k_oproj(
    const bf16* __restrict__ att, const bf16* __restrict__ Wto,
    const float* __restrict__ bo, float* __restrict__ out)
{
    __shared__ uint4 Al[2][512];
    __shared__ uint4 Bl[2][512];

    const int tid  = threadIdx.x;
    const int w    = tid >> 6;
    const int lane = tid & 63;
    const int col  = lane & 15;
    const int quad = lane >> 4;
    const int m0 = blockIdx.x * 128;
    const int n0 = blockIdx.y * 128;

    const bf16* gA0 = att + (size_t)(m0 + (tid >> 2)) * 512 + (tid & 3) * 8;
    const bf16* gA1 = gA0 + 64 * 512;
    const bf16* gB0 = Wto + (size_t)(n0 + (tid >> 2)) * 512 + (tid & 3) * 8;
    const bf16* gB1 = gB0 + 64 * 512;

    const floatx4 zf = {0.f, 0.f, 0.f, 0.f};
    floatx4 acc[4][4];
    #pragma unroll
    for (int a = 0; a < 4; ++a)
        #pragma unroll
        for (int b = 0; b < 4; ++b) acc[a][b] = zf;

    Al[0][tid]       = *(const uint4*)gA0;
    Al[0][tid + 256] = *(const uint4*)gA1;
    Bl[0][tid]       = *(const uint4*)gB0;
    Bl[0][tid + 256] = *(const uint4*)gB1;
    __syncthreads();

    const int mb = (w & 1) * 64;
    const int nb = (w >> 1) * 64;

    int buf = 0;
    for (int kk = 0; kk < 16; ++kk) {
        const int kn = ((kk + 1) & 15) * 32;
        const uint4 pa0 = *(const uint4*)(gA0 + kn);
        const uint4 pa1 = *(const uint4*)(gA1 + kn);
        const uint4 pb0 = *(const uint4*)(gB0 + kn);
        const uint4 pb1 = *(const uint4*)(gB1 + kn);

        const uint4* A4 = Al[buf];
        const uint4* B4 = Bl[buf];
        bf16x8 af[4], bfr[4];
        #pragma unroll
        for (int t = 0; t < 4; ++t) {
            union { uint4 u; bf16x8 v; } ca, cb;
            ca.u = A4[(mb + 16 * t + col) * 4 + quad];
            cb.u = B4[(nb + 16 * t + col) * 4 + quad];
            af[t] = ca.v;
            bfr[t] = cb.v;
        }
        #pragma unroll
        for (int tm = 0; tm < 4; ++tm)
            #pragma unroll
            for (int tn = 0; tn < 4; ++tn)
                acc[tm][tn] = MFMA32(af[tm], bfr[tn], acc[tm][tn]);

        Al[buf ^ 1][tid]       = pa0;
        Al[buf ^ 1][tid + 256] = pa1;
        Bl[buf ^ 1][tid]       = pb0;
        Bl[buf ^ 1][tid + 256] = pb1;
        __syncthreads();
        buf ^= 1;
    }

    #pragma unroll
    for (int tn = 0; tn < 4; ++tn) {
        const int n = n0 + nb + 16 * tn + col;
        const float bb = bo[n];
        #pragma unroll
        for (int tm = 0; tm < 4; ++tm)
            #pragma unroll
            for (int r = 0; r < 4; ++r) {
                const int m = m0 + mb + 16 * tm + quad * 4 + r;
                out[(size_t)m * 512 + n] = acc[tm][tn][r] + bb;
            }
    }
}

// ---------------------------------------------------------------------------
extern "C" void kernel_launch(void* const* d_in, const int* in_sizes, int n_in,
                              void* d_out, int out_size, void* d_ws, size_t ws_size,
                              hipStream_t stream)
{
    const float* X  = (const float*)d_in[0];
    const float* Wq = (const float*)d_in[1];
    const float* bq = (const float*)d_in[2];
    const float* Wk = (const float*)d_in[3];
    const float* bk = (const float*)d_in[4];
    const float* Wv = (const float*)d_in[5];
    const float* bv = (const float*)d_in[6];
    const float* Wo = (const float*)d_in[7];
    const float* bo = (const float*)d_in[8];

    // workspace (bf16 elements): Wcat(3) + Wto + Q + K + Vt + att = 34.1 MB
    bf16* Wtq = (bf16*)d_ws;                   // rows 0..511 of Wcat
    bf16* Wtk = Wtq + 512 * 512;               // rows 512..1023
    bf16* Wtv = Wtk + 512 * 512;               // rows 1024..1535
    bf16* Wto = Wtv + 512 * 512;
    bf16* Qs  = Wto + 512 * 512;               // [16][4096][64]
    bf16* Ks  = Qs + (size_t)16 * 4096 * 64;   // [16][4096][64]
    bf16* Vt  = Ks + (size_t)16 * 4096 * 64;   // [16][64][4096]
    bf16* att = Vt + (size_t)16 * 4096 * 64;   // [8192][512]

    bf16* Xb  = (bf16*)d_out;                  // scratch; consumed by k_qkv,
                                               // d_out rewritten only by k_oproj

    k_transpose<<<dim3(16, 16, 4), 256, 0, stream>>>(Wq, Wk, Wv, Wo, Wtq, Wtk, Wtv, Wto);
    k_cvtx<<<2048, 256, 0, stream>>>(X, Xb);
    k_qkv<<<dim3(64, 12), 256, 0, stream>>>(Xb, Wtq, bq, bk, bv, Qs, Ks, Vt);
    k_attn<<<512, 256, 0, stream>>>(Qs, Ks, Vt, att);
    k_oproj<<<dim3(64, 4), 256, 0, stream>>>(att, Wto, bo, (float*)d_out);
}

// Round 9
// 219.868 us; speedup vs baseline: 2.1342x; 1.1425x over previous
//
#include <hip/hip_runtime.h>
#include <cstdint>

typedef __bf16 bf16;
typedef __bf16 bf16x8 __attribute__((ext_vector_type(8)));
typedef float floatx4 __attribute__((ext_vector_type(4)));

#define MFMA32(a, b, c) __builtin_amdgcn_mfma_f32_16x16x32_bf16((a), (b), (c), 0, 0, 0)

__device__ inline bf16x8 cvt8(const float* p) {
    float4 u = *(const float4*)p;
    float4 v = *(const float4*)(p + 4);
    bf16x8 r;
    r[0] = (bf16)u.x; r[1] = (bf16)u.y; r[2] = (bf16)u.z; r[3] = (bf16)u.w;
    r[4] = (bf16)v.x; r[5] = (bf16)v.y; r[6] = (bf16)v.z; r[7] = (bf16)v.w;
    return r;
}

// ---------------------------------------------------------------------------
// Kernel 1: transpose + fp32->bf16 convert the four 512x512 weight matrices.
// ---------------------------------------------------------------------------
__global__ __launch_bounds__(256) void k_transpose(
    const float* __restrict__ w0, const float* __restrict__ w1,
    const float* __restrict__ w2, const float* __restrict__ w3,
    bf16* __restrict__ o0, bf16* __restrict__ o1,
    bf16* __restrict__ o2, bf16* __restrict__ o3)
{
    __shared__ float t[32][33];
    const float* in;
    bf16* out;
    switch (blockIdx.z) {
        case 0: in = w0; out = o0; break;
        case 1: in = w1; out = o1; break;
        case 2: in = w2; out = o2; break;
        default: in = w3; out = o3; break;
    }
    const int tx = threadIdx.x & 31;
    const int ty = threadIdx.x >> 5;
    const int r0 = blockIdx.y * 32;
    const int c0 = blockIdx.x * 32;
    #pragma unroll
    for (int i = 0; i < 32; i += 8)
        t[ty + i][tx] = in[(size_t)(r0 + ty + i) * 512 + c0 + tx];
    __syncthreads();
    #pragma unroll
    for (int i = 0; i < 32; i += 8)
        out[(size_t)(c0 + ty + i) * 512 + r0 + tx] = (bf16)t[tx][ty + i];
}

// ---------------------------------------------------------------------------
// Kernel 1b: X fp32 -> bf16 into d_out scratch (consumed by k_qkv).
// ---------------------------------------------------------------------------
__global__ __launch_bounds__(256) void k_cvtx(
    const float* __restrict__ X, bf16* __restrict__ Xb)
{
    const size_t idx = ((size_t)blockIdx.x * 256 + threadIdx.x) * 8;
    *(bf16x8*)(Xb + idx) = cvt8(X + idx);
}

// ---------------------------------------------------------------------------
// Kernel 2: QKV GEMM (128x128 tile, BK=32, double-buffered LDS) + per-wave
// LDS-transpose epilogue. Each wave's 64x64 tile spans exactly one head, so
// phase A writes acc(+bias/scale) into a wave-private LDS tile ([s][d] for
// Q/K, [d][s] for V, stride 72) and phase B emits fully-coalesced 128B
// global_store_dwordx4 rows. GEMM LDS is reused post-final-barrier
// (wave-private regions; asm memory clobber stops TBAA reordering).
// ---------------------------------------------------------------------------
__global__ __launch_bounds__(256) void k_qkv(
    const bf16* __restrict__ Xb, const bf16* __restrict__ Wcat,
    const float* __restrict__ bq, const float* __restrict__ bk, const float* __restrict__ bv,
    bf16* __restrict__ Qs, bf16* __restrict__ Ks, bf16* __restrict__ Vt)
{
    __shared__ __align__(16) unsigned char smem[36864];   // 36 KB
    uint4* Al = (uint4*)smem;              // [2][512]
    uint4* Bl = (uint4*)(smem + 16384);    // [2][512]

    const int tid  = threadIdx.x;
    const int w    = tid >> 6;
    const int lane = tid & 63;
    const int col  = lane & 15;
    const int quad = lane >> 4;
    const int m0 = blockIdx.x * 128;
    const int n0 = blockIdx.y * 128;

    const bf16* gA0 = Xb   + (size_t)(m0 + (tid >> 2)) * 512 + (tid & 3) * 8;
    const bf16* gA1 = gA0 + 64 * 512;
    const bf16* gB0 = Wcat + (size_t)(n0 + (tid >> 2)) * 512 + (tid & 3) * 8;
    const bf16* gB1 = gB0 + 64 * 512;

    const floatx4 zf = {0.f, 0.f, 0.f, 0.f};
    floatx4 acc[4][4];
    #pragma unroll
    for (int a = 0; a < 4; ++a)
        #pragma unroll
        for (int b = 0; b < 4; ++b) acc[a][b] = zf;

    Al[tid]       = *(const uint4*)gA0;
    Al[tid + 256] = *(const uint4*)gA1;
    Bl[tid]       = *(const uint4*)gB0;
    Bl[tid + 256] = *(const uint4*)gB1;
    __syncthreads();

    const int mb = (w & 1) * 64;
    const int nb = (w >> 1) * 64;

    int buf = 0;
    for (int kk = 0; kk < 16; ++kk) {
        const int kn = ((kk + 1) & 15) * 32;
        const uint4 pa0 = *(const uint4*)(gA0 + kn);
        const uint4 pa1 = *(const uint4*)(gA1 + kn);
        const uint4 pb0 = *(const uint4*)(gB0 + kn);
        const uint4 pb1 = *(const uint4*)(gB1 + kn);

        const uint4* A4 = Al + buf * 512;
        const uint4* B4 = Bl + buf * 512;
        bf16x8 af[4], bfr[4];
        #pragma unroll
        for (int t = 0; t < 4; ++t) {
            union { uint4 u; bf16x8 v; } ca, cb;
            ca.u = A4[(mb + 16 * t + col) * 4 + quad];
            cb.u = B4[(nb + 16 * t + col) * 4 + quad];
            af[t] = ca.v;
            bfr[t] = cb.v;
        }
        #pragma unroll
        for (int tm = 0; tm < 4; ++tm)
            #pragma unroll
            for (int tn = 0; tn < 4; ++tn)
                acc[tm][tn] = MFMA32(af[tm], bfr[tn], acc[tm][tn]);

        const int nbuf = buf ^ 1;
        Al[nbuf * 512 + tid]       = pa0;
        Al[nbuf * 512 + tid + 256] = pa1;
        Bl[nbuf * 512 + tid]       = pb0;
        Bl[nbuf * 512 + tid + 256] = pb1;
        __syncthreads();
        buf = nbuf;
    }

    // ---- epilogue: wave-private LDS transpose, coalesced 128B stores ----
    bf16* ep = (bf16*)smem + (size_t)w * 64 * 72;   // 9216 B per wave

    const int which = blockIdx.y >> 2;              // 0=Q 1=K 2=V
    const int nbase = (blockIdx.y & 3) * 128 + nb;  // 64-aligned
    const int h  = nbase >> 6;
    const int mw = m0 + mb;                         // wave's first m (64-aligned)
    const int b  = mw >> 12;
    const int s0 = mw & 4095;
    const float qsc = 0.125f * 1.44269504088896f;

    if (which == 2) {
        // V: LDS [d][s], packed b64 along consecutive s (r)
        #pragma unroll
        for (int tn = 0; tn < 4; ++tn) {
            const int d = 16 * tn + col;
            const float bb = bv[nbase + d];
            #pragma unroll
            for (int tm = 0; tm < 4; ++tm) {
                union { bf16 e[4]; uint2 u; } pk;
                #pragma unroll
                for (int r = 0; r < 4; ++r) pk.e[r] = (bf16)(acc[tm][tn][r] + bb);
                *(uint2*)(ep + d * 72 + 16 * tm + 4 * quad) = pk.u;
            }
        }
    } else {
        // Q/K: LDS [s][d], scalar writes (4 strided s-rows per value group)
        const float* bias = (which == 0) ? bq : bk;
        const float sc = (which == 0) ? qsc : 1.0f;
        #pragma unroll
        for (int tn = 0; tn < 4; ++tn) {
            const int d = 16 * tn + col;
            const float bb = bias[nbase + d];
            #pragma unroll
            for (int tm = 0; tm < 4; ++tm)
                #pragma unroll
                for (int r = 0; r < 4; ++r)
                    ep[(16 * tm + 4 * quad + r) * 72 + d] = (bf16)((acc[tm][tn][r] + bb) * sc);
        }
    }

    asm volatile("" ::: "memory");   // order phase-A LDS writes before phase-B reads

    const int rl = lane >> 3;        // 0..7
    const int ch = lane & 7;         // 0..7
    bf16* gbase;
    size_t rowstride;
    if (which == 2) {
        gbase = Vt + (((size_t)b * 8 + h) * 64) * 4096 + s0;
        rowstride = 4096;
    } else {
        bf16* P = (which == 0) ? Qs : Ks;
        gbase = P + (((size_t)b * 8 + h) * 4096 + s0) * 64;
        rowstride = 64;
    }
    #pragma unroll
    for (int it = 0; it < 8; ++it) {
        const int row = it * 8 + rl;
        const uint4 v = *(const uint4*)(ep + row * 72 + ch * 8);
        *(uint4*)(gbase + (size_t)row * rowstride + ch * 8) = v;
    }
}

// ---------------------------------------------------------------------------
// Kernel 3: attention (R6/R8 structure). 512 blocks (2/CU), 128 q/block,
// 32/wave. K/V tiles double-buffered in swizzled LDS shared by 4 waves;
// P via wave-private uint32 LDS; one barrier/iter. Streaming softmax with
// RAW v_exp_f32 (__builtin_amdgcn_exp2f; Q pre-scaled by 0.125*log2e).
// ---------------------------------------------------------------------------
__global__ __launch_bounds__(256, 2) void k_attn(
    const bf16* __restrict__ Qs, const bf16* __restrict__ Ks, const bf16* __restrict__ Vt,
    bf16* __restrict__ att)
{
    __shared__ uint4 Klds[2][256];
    __shared__ uint4 Vlds[2][256];
    __shared__ uint32_t Pt_all[4 * 32 * 17];

    const int tid  = threadIdx.x;
    const int w    = tid >> 6;
    const int lane = tid & 63;
    const int col  = lane & 15;
    const int quad = lane >> 4;
    const int i    = blockIdx.x;
    const int bh   = ((i & 7) << 1) | ((i >> 3) & 1);   // 2 heads per XCD
    const int q0   = (i >> 4) * 128 + w * 32;

    const bf16* Qb = Qs + (size_t)bh * 262144;
    const bf16* Kb = Ks + (size_t)bh * 262144;
    const bf16* Vb = Vt + (size_t)bh * 262144;
    uint32_t* Pt = Pt_all + w * 32 * 17;

    const int rK  = tid >> 3;
    const int lcK = (tid & 7) ^ (rK & 7);
    const bf16* gK = Kb + (size_t)rK * 64 + lcK * 8;
    const int pV  = tid >> 3;
    const int ccV = (tid & 7) ^ (pV & 7);
    const int dV  = 2 * pV + (ccV >> 2);
    const int cV  = ccV & 3;
    const bf16* gV = Vb + (size_t)dV * 4096 + cV * 8;

    bf16x8 aq[2][2];
    #pragma unroll
    for (int s = 0; s < 2; ++s)
        #pragma unroll
        for (int c = 0; c < 2; ++c)
            aq[s][c] = *(const bf16x8*)(Qb + (size_t)(q0 + 16 * s + col) * 64 + 32 * c + quad * 8);

    const floatx4 zf = {0.f, 0.f, 0.f, 0.f};
    floatx4 o[2][4];
    float l[2][4];
    #pragma unroll
    for (int s = 0; s < 2; ++s) {
        #pragma unroll
        for (int t = 0; t < 4; ++t) o[s][t] = zf;
        #pragma unroll
        for (int r = 0; r < 4; ++r) l[s][r] = 0.f;
    }

    const uint32_t sel = (col & 1) ? 0x07060302u : 0x05040100u;

    Klds[0][tid] = *(const uint4*)gK;
    Vlds[0][tid] = *(const uint4*)gV;
    __syncthreads();

    int buf = 0;
    for (int kt = 0; kt < 4096; kt += 32) {
        const int kn = (kt + 32) & 4095;
        const uint4 kreg = *(const uint4*)(gK + (size_t)kn * 64);
        const uint4 vreg = *(const uint4*)(gV + kn);

        const uint4* Kl = Klds[buf];
        const uint4* Vl = Vlds[buf];
        bf16x8 kf[2][2], vf[4];
        #pragma unroll
        for (int t = 0; t < 2; ++t)
            #pragma unroll
            for (int h = 0; h < 2; ++h) {
                union { uint4 u; bf16x8 v; } cv;
                cv.u = Kl[(16 * t + col) * 8 + ((quad + 4 * h) ^ (col & 7))];
                kf[t][h] = cv.v;
            }
        #pragma unroll
        for (int t = 0; t < 4; ++t) {
            union { uint4 u; bf16x8 v; } cv;
            cv.u = Vl[(8 * t + (col >> 1)) * 8 + ((((col & 1) * 4) + quad) ^ ((col >> 1) & 7))];
            vf[t] = cv.v;
        }

        #pragma unroll
        for (int s = 0; s < 2; ++s) {
            #pragma unroll
            for (int t = 0; t < 2; ++t) {
                floatx4 sc = MFMA32(aq[s][1], kf[t][1], MFMA32(aq[s][0], kf[t][0], zf));
                float p0 = __builtin_amdgcn_exp2f(sc[0]);
                float p1 = __builtin_amdgcn_exp2f(sc[1]);
                float p2 = __builtin_amdgcn_exp2f(sc[2]);
                float p3 = __builtin_amdgcn_exp2f(sc[3]);
                l[s][0] += p0; l[s][1] += p1; l[s][2] += p2; l[s][3] += p3;
                union { bf16 e[4]; uint32_t u[2]; } pk;
                pk.e[0] = (bf16)p0; pk.e[1] = (bf16)p1;
                pk.e[2] = (bf16)p2; pk.e[3] = (bf16)p3;
                uint32_t* dst = Pt + (16 * t + col) * 17 + 8 * s + 2 * quad;
                dst[0] = pk.u[0];
                dst[1] = pk.u[1];
            }
        }
        #pragma unroll
        for (int s = 0; s < 2; ++s) {
            uint32_t wd[8];
            #pragma unroll
            for (int j = 0; j < 8; ++j)
                wd[j] = Pt[(quad * 8 + j) * 17 + 8 * s + (col >> 1)];
            union { uint32_t u[4]; bf16x8 v; } ap;
            #pragma unroll
            for (int ii = 0; ii < 4; ++ii)
                ap.u[ii] = __builtin_amdgcn_perm(wd[2 * ii + 1], wd[2 * ii], sel);
            #pragma unroll
            for (int t = 0; t < 4; ++t)
                o[s][t] = MFMA32(ap.v, vf[t], o[s][t]);
        }

        Klds[buf ^ 1][tid] = kreg;
        Vlds[buf ^ 1][tid] = vreg;
        __syncthreads();
        buf ^= 1;
    }

    #pragma unroll
    for (int s = 0; s < 2; ++s)
        #pragma unroll
        for (int r = 0; r < 4; ++r) {
            float v = l[s][r];
            v += __shfl_xor(v, 1, 64);
            v += __shfl_xor(v, 2, 64);
            v += __shfl_xor(v, 4, 64);
            v += __shfl_xor(v, 8, 64);
            l[s][r] = 1.0f / v;
        }

    const int b = bh >> 3;
    const int h = bh & 7;
    #pragma unroll
    for (int s = 0; s < 2; ++s)
        #pragma unroll
        for (int t = 0; t < 4; ++t)
            #pragma unroll
            for (int r = 0; r < 4; ++r) {
                const size_t row = (size_t)b * 4096 + q0 + 16 * s + 4 * quad + r;
                att[row * 512 + h * 64 + 16 * t + col] = (bf16)(o[s][t][r] * l[s][r]);
            }
}

// ---------------------------------------------------------------------------
// Kernel 4: output projection GEMM. out[8192][512] fp32 = att @ Wto^T + bo.
// ---------------------------------------------------------------------------
__global__ __launch_bounds__(256) void k_oproj(
    const bf16* __restrict__ att, const bf16* __restrict__ Wto,
    const float* __restrict__ bo, float* __restrict__ out)
{
    __shared__ uint4 Al[2][512];
    __shared__ uint4 Bl[2][512];

    const int tid  = threadIdx.x;
    const int w    = tid >> 6;
    const int lane = tid & 63;
    const int col  = lane & 15;
    const int quad = lane >> 4;
    const int m0 = blockIdx.x * 128;
    const int n0 = blockIdx.y * 128;

    const bf16* gA0 = att + (size_t)(m0 + (tid >> 2)) * 512 + (tid & 3) * 8;
    const bf16* gA1 = gA0 + 64 * 512;
    const bf16* gB0 = Wto + (size_t)(n0 + (tid >> 2)) * 512 + (tid & 3) * 8;
    const bf16* gB1 = gB0 + 64 * 512;

    const floatx4 zf = {0.f, 0.f, 0.f, 0.f};
    floatx4 acc[4][4];
    #pragma unroll
    for (int a = 0; a < 4; ++a)
        #pragma unroll
        for (int b = 0; b < 4; ++b) acc[a][b] = zf;

    Al[0][tid]       = *(const uint4*)gA0;
    Al[0][tid + 256] = *(const uint4*)gA1;
    Bl[0][tid]       = *(const uint4*)gB0;
    Bl[0][tid + 256] = *(const uint4*)gB1;
    __syncthreads();

    const int mb = (w & 1) * 64;
    const int nb = (w >> 1) * 64;

    int buf = 0;
    for (int kk = 0; kk < 16; ++kk) {
        const int kn = ((kk + 1) & 15) * 32;
        const uint4 pa0 = *(const uint4*)(gA0 + kn);
        const uint4 pa1 = *(const uint4*)(gA1 + kn);
        const uint4 pb0 = *(const uint4*)(gB0 + kn);
        const uint4 pb1 = *(const uint4*)(gB1 + kn);

        const uint4* A4 = Al[buf];
        const uint4* B4 = Bl[buf];
        bf16x8 af[4], bfr[4];
        #pragma unroll
        for (int t = 0; t < 4; ++t) {
            union { uint4 u; bf16x8 v; } ca, cb;
            ca.u = A4[(mb + 16 * t + col) * 4 + quad];
            cb.u = B4[(nb + 16 * t + col) * 4 + quad];
            af[t] = ca.v;
            bfr[t] = cb.v;
        }
        #pragma unroll
        for (int tm = 0; tm < 4; ++tm)
            #pragma unroll
            for (int tn = 0; tn < 4; ++tn)
                acc[tm][tn] = MFMA32(af[tm], bfr[tn], acc[tm][tn]);

        Al[buf ^ 1][tid]       = pa0;
        Al[buf ^ 1][tid + 256] = pa1;
        Bl[buf ^ 1][tid]       = pb0;
        Bl[buf ^ 1][tid + 256] = pb1;
        __syncthreads();
        buf ^= 1;
    }

    #pragma unroll
    for (int tn = 0; tn < 4; ++tn) {
        const int n = n0 + nb + 16 * tn + col;
        const float bb = bo[n];
        #pragma unroll
        for (int tm = 0; tm < 4; ++tm)
            #pragma unroll
            for (int r = 0; r < 4; ++r) {
                const int m = m0 + mb + 16 * tm + quad * 4 + r;
                out[(size_t)m * 512 + n] = acc[tm][tn][r] + bb;
            }
    }
}

// ---------------------------------------------------------------------------
extern "C" void kernel_launch(void* const* d_in, const int* in_sizes, int n_in,
                              void* d_out, int out_size, void* d_ws, size_t ws_size,
                              hipStream_t stream)
{
    const float* X  = (const float*)d_in[0];
    const float* Wq = (const float*)d_in[1];
    const float* bq = (const float*)d_in[2];
    const float* Wk = (const float*)d_in[3];
    const float* bk = (const float*)d_in[4];
    const float* Wv = (const float*)d_in[5];
    const float* bv = (const float*)d_in[6];
    const float* Wo = (const float*)d_in[7];
    const float* bo = (const float*)d_in[8];

    // workspace (bf16 elements): Wcat(3) + Wto + Q + K + Vt + att = 34.1 MB
    bf16* Wtq = (bf16*)d_ws;                   // rows 0..511 of Wcat
    bf16* Wtk = Wtq + 512 * 512;               // rows 512..1023
    bf16* Wtv = Wtk + 512 * 512;               // rows 1024..1535
    bf16* Wto = Wtv + 512 * 512;
    bf16* Qs  = Wto + 512 * 512;               // [16][4096][64]
    bf16* Ks  = Qs + (size_t)16 * 4096 * 64;   // [16][4096][64]
    bf16* Vt  = Ks + (size_t)16 * 4096 * 64;   // [16][64][4096]
    bf16* att = Vt + (size_t)16 * 4096 * 64;   // [8192][512]

    bf16* Xb  = (bf16*)d_out;                  // scratch; consumed by k_qkv,
                                               // d_out rewritten only by k_oproj

    k_transpose<<<dim3(16, 16, 4), 256, 0, stream>>>(Wq, Wk, Wv, Wo, Wtq, Wtk, Wtv, Wto);
    k_cvtx<<<2048, 256, 0, stream>>>(X, Xb);
    k_qkv<<<dim3(64, 12), 256, 0, stream>>>(Xb, Wtq, bq, bk, bv, Qs, Ks, Vt);
    k_attn<<<512, 256, 0, stream>>>(Qs, Ks, Vt, att);
    k_oproj<<<dim3(64, 4), 256, 0, stream>>>(att, Wto, bo, (float*)d_out);
}

// Round 10
// 205.105 us; speedup vs baseline: 2.2878x; 1.0720x over previous
//
#include <hip/hip_runtime.h>
#include <cstdint>

typedef __bf16 bf16;
typedef __bf16 bf16x4 __attribute__((ext_vector_type(4)));
typedef __bf16 bf16x8 __attribute__((ext_vector_type(8)));
typedef float floatx4 __attribute__((ext_vector_type(4)));

#define MFMA32(a, b, c) __builtin_amdgcn_mfma_f32_16x16x32_bf16((a), (b), (c), 0, 0, 0)
#define MFMA16(a, b, c) __builtin_amdgcn_mfma_f32_16x16x16bf16_1k((a), (b), (c), 0, 0, 0)

__device__ inline bf16x8 cvt8(const float* p) {
    float4 u = *(const float4*)p;
    float4 v = *(const float4*)(p + 4);
    bf16x8 r;
    r[0] = (bf16)u.x; r[1] = (bf16)u.y; r[2] = (bf16)u.z; r[3] = (bf16)u.w;
    r[4] = (bf16)v.x; r[5] = (bf16)v.y; r[6] = (bf16)v.z; r[7] = (bf16)v.w;
    return r;
}

// ---------------------------------------------------------------------------
// Kernel 1: transpose + fp32->bf16 convert the four 512x512 weight matrices.
// ---------------------------------------------------------------------------
__global__ __launch_bounds__(256) void k_transpose(
    const float* __restrict__ w0, const float* __restrict__ w1,
    const float* __restrict__ w2, const float* __restrict__ w3,
    bf16* __restrict__ o0, bf16* __restrict__ o1,
    bf16* __restrict__ o2, bf16* __restrict__ o3)
{
    __shared__ float t[32][33];
    const float* in;
    bf16* out;
    switch (blockIdx.z) {
        case 0: in = w0; out = o0; break;
        case 1: in = w1; out = o1; break;
        case 2: in = w2; out = o2; break;
        default: in = w3; out = o3; break;
    }
    const int tx = threadIdx.x & 31;
    const int ty = threadIdx.x >> 5;
    const int r0 = blockIdx.y * 32;
    const int c0 = blockIdx.x * 32;
    #pragma unroll
    for (int i = 0; i < 32; i += 8)
        t[ty + i][tx] = in[(size_t)(r0 + ty + i) * 512 + c0 + tx];
    __syncthreads();
    #pragma unroll
    for (int i = 0; i < 32; i += 8)
        out[(size_t)(c0 + ty + i) * 512 + r0 + tx] = (bf16)t[tx][ty + i];
}

// ---------------------------------------------------------------------------
// Kernel 1b: X fp32 -> bf16 into d_out scratch (consumed by k_qkv).
// ---------------------------------------------------------------------------
__global__ __launch_bounds__(256) void k_cvtx(
    const float* __restrict__ X, bf16* __restrict__ Xb)
{
    const size_t idx = ((size_t)blockIdx.x * 256 + threadIdx.x) * 8;
    *(bf16x8*)(Xb + idx) = cvt8(X + idx);
}

// ---------------------------------------------------------------------------
// Kernel 2: QKV GEMM (128x128 tile, BK=32, double-buffered LDS) + per-wave
// LDS-transpose epilogue (coalesced 128B stores). Same as R9.
// ---------------------------------------------------------------------------
__global__ __launch_bounds__(256) void k_qkv(
    const bf16* __restrict__ Xb, const bf16* __restrict__ Wcat,
    const float* __restrict__ bq, const float* __restrict__ bk, const float* __restrict__ bv,
    bf16* __restrict__ Qs, bf16* __restrict__ Ks, bf16* __restrict__ Vt)
{
    __shared__ __align__(16) unsigned char smem[36864];   // 36 KB
    uint4* Al = (uint4*)smem;              // [2][512]
    uint4* Bl = (uint4*)(smem + 16384);    // [2][512]

    const int tid  = threadIdx.x;
    const int w    = tid >> 6;
    const int lane = tid & 63;
    const int col  = lane & 15;
    const int quad = lane >> 4;
    const int m0 = blockIdx.x * 128;
    const int n0 = blockIdx.y * 128;

    const bf16* gA0 = Xb   + (size_t)(m0 + (tid >> 2)) * 512 + (tid & 3) * 8;
    const bf16* gA1 = gA0 + 64 * 512;
    const bf16* gB0 = Wcat + (size_t)(n0 + (tid >> 2)) * 512 + (tid & 3) * 8;
    const bf16* gB1 = gB0 + 64 * 512;

    const floatx4 zf = {0.f, 0.f, 0.f, 0.f};
    floatx4 acc[4][4];
    #pragma unroll
    for (int a = 0; a < 4; ++a)
        #pragma unroll
        for (int b = 0; b < 4; ++b) acc[a][b] = zf;

    Al[tid]       = *(const uint4*)gA0;
    Al[tid + 256] = *(const uint4*)gA1;
    Bl[tid]       = *(const uint4*)gB0;
    Bl[tid + 256] = *(const uint4*)gB1;
    __syncthreads();

    const int mb = (w & 1) * 64;
    const int nb = (w >> 1) * 64;

    int buf = 0;
    for (int kk = 0; kk < 16; ++kk) {
        const int kn = ((kk + 1) & 15) * 32;
        const uint4 pa0 = *(const uint4*)(gA0 + kn);
        const uint4 pa1 = *(const uint4*)(gA1 + kn);
        const uint4 pb0 = *(const uint4*)(gB0 + kn);
        const uint4 pb1 = *(const uint4*)(gB1 + kn);

        const uint4* A4 = Al + buf * 512;
        const uint4* B4 = Bl + buf * 512;
        bf16x8 af[4], bfr[4];
        #pragma unroll
        for (int t = 0; t < 4; ++t) {
            union { uint4 u; bf16x8 v; } ca, cb;
            ca.u = A4[(mb + 16 * t + col) * 4 + quad];
            cb.u = B4[(nb + 16 * t + col) * 4 + quad];
            af[t] = ca.v;
            bfr[t] = cb.v;
        }
        #pragma unroll
        for (int tm = 0; tm < 4; ++tm)
            #pragma unroll
            for (int tn = 0; tn < 4; ++tn)
                acc[tm][tn] = MFMA32(af[tm], bfr[tn], acc[tm][tn]);

        const int nbuf = buf ^ 1;
        Al[nbuf * 512 + tid]       = pa0;
        Al[nbuf * 512 + tid + 256] = pa1;
        Bl[nbuf * 512 + tid]       = pb0;
        Bl[nbuf * 512 + tid + 256] = pb1;
        __syncthreads();
        buf = nbuf;
    }

    // ---- epilogue: wave-private LDS transpose, coalesced 128B stores ----
    bf16* ep = (bf16*)smem + (size_t)w * 64 * 72;   // 9216 B per wave

    const int which = blockIdx.y >> 2;              // 0=Q 1=K 2=V
    const int nbase = (blockIdx.y & 3) * 128 + nb;  // 64-aligned
    const int h  = nbase >> 6;
    const int mw = m0 + mb;
    const int b  = mw >> 12;
    const int s0 = mw & 4095;
    const float qsc = 0.125f * 1.44269504088896f;

    if (which == 2) {
        #pragma unroll
        for (int tn = 0; tn < 4; ++tn) {
            const int d = 16 * tn + col;
            const float bb = bv[nbase + d];
            #pragma unroll
            for (int tm = 0; tm < 4; ++tm) {
                union { bf16 e[4]; uint2 u; } pk;
                #pragma unroll
                for (int r = 0; r < 4; ++r) pk.e[r] = (bf16)(acc[tm][tn][r] + bb);
                *(uint2*)(ep + d * 72 + 16 * tm + 4 * quad) = pk.u;
            }
        }
    } else {
        const float* bias = (which == 0) ? bq : bk;
        const float sc = (which == 0) ? qsc : 1.0f;
        #pragma unroll
        for (int tn = 0; tn < 4; ++tn) {
            const int d = 16 * tn + col;
            const float bb = bias[nbase + d];
            #pragma unroll
            for (int tm = 0; tm < 4; ++tm)
                #pragma unroll
                for (int r = 0; r < 4; ++r)
                    ep[(16 * tm + 4 * quad + r) * 72 + d] = (bf16)((acc[tm][tn][r] + bb) * sc);
        }
    }

    asm volatile("" ::: "memory");

    const int rl = lane >> 3;
    const int ch = lane & 7;
    bf16* gbase;
    size_t rowstride;
    if (which == 2) {
        gbase = Vt + (((size_t)b * 8 + h) * 64) * 4096 + s0;
        rowstride = 4096;
    } else {
        bf16* P = (which == 0) ? Qs : Ks;
        gbase = P + (((size_t)b * 8 + h) * 4096 + s0) * 64;
        rowstride = 64;
    }
    #pragma unroll
    for (int it = 0; it < 8; ++it) {
        const int row = it * 8 + rl;
        const uint4 v = *(const uint4*)(ep + row * 72 + ch * 8);
        *(uint4*)(gbase + (size_t)row * rowstride + ch * 8) = v;
    }
}

// ---------------------------------------------------------------------------
// Kernel 3: attention, transposed-score + in-lane P (no P LDS round-trip).
// S^T = K*Q^T via MFMA32 (swapped operands, same registers): C-layout gives
// each lane 4 KEYS at one q-col = B-fragment of mfma_f32_16x16x16bf16_1k,
// so exp feeds O^T = V^T*P^T fully in-lane (correctness proven in R7).
// Kept from R6/R9: 256-thr blocks, 512 blocks (2/CU, 8 waves/CU), 32 q/wave,
// double-buffered swizzled K/V LDS staging, one barrier/iter, streaming
// softmax with raw v_exp (Q pre-scaled 0.125*log2e). V-fragments are b64
// reads from the staged tile (4-phase floor, conflict-free).
// ---------------------------------------------------------------------------
__global__ __launch_bounds__(256, 2) void k_attn(
    const bf16* __restrict__ Qs, const bf16* __restrict__ Ks, const bf16* __restrict__ Vt,
    bf16* __restrict__ att)
{
    __shared__ uint4 Klds[2][256];
    __shared__ uint4 Vlds[2][256];

    const int tid  = threadIdx.x;
    const int w    = tid >> 6;
    const int lane = tid & 63;
    const int col  = lane & 15;
    const int quad = lane >> 4;
    const int i    = blockIdx.x;
    const int bh   = ((i & 7) << 1) | ((i >> 3) & 1);   // 2 heads per XCD
    const int q0   = (i >> 4) * 128 + w * 32;

    const bf16* Qb = Qs + (size_t)bh * 262144;
    const bf16* Kb = Ks + (size_t)bh * 262144;
    const bf16* Vb = Vt + (size_t)bh * 262144;

    const int rK  = tid >> 3;
    const int lcK = (tid & 7) ^ (rK & 7);
    const bf16* gK = Kb + (size_t)rK * 64 + lcK * 8;
    const int pV  = tid >> 3;
    const int ccV = (tid & 7) ^ (pV & 7);
    const int dV  = 2 * pV + (ccV >> 2);
    const int cV  = ccV & 3;
    const bf16* gV = Vb + (size_t)dV * 4096 + cV * 8;

    // Q fragments (B-operand of S^T MFMA): 2 q-sets x 2 dim-halves
    bf16x8 aq[2][2];
    #pragma unroll
    for (int s = 0; s < 2; ++s)
        #pragma unroll
        for (int c = 0; c < 2; ++c)
            aq[s][c] = *(const bf16x8*)(Qb + (size_t)(q0 + 16 * s + col) * 64 + 32 * c + quad * 8);

    const floatx4 zf = {0.f, 0.f, 0.f, 0.f};
    floatx4 o[2][4];                 // O^T: [qset][d-tile]; lane d=4quad+r, q=col
    float lsum[2] = {0.f, 0.f};
    #pragma unroll
    for (int s = 0; s < 2; ++s)
        #pragma unroll
        for (int dt = 0; dt < 4; ++dt) o[s][dt] = zf;

    // V b64 read geometry (from the pair-swizzled uint4 tile)
    const int c1 = col & 1, ch = col >> 1, qh = quad >> 1, ql = quad & 1;

    Klds[0][tid] = *(const uint4*)gK;
    Vlds[0][tid] = *(const uint4*)gV;
    __syncthreads();

    int buf = 0;
    for (int kt = 0; kt < 4096; kt += 32) {
        const int kn = (kt + 32) & 4095;
        const uint4 kreg = *(const uint4*)(gK + (size_t)kn * 64);
        const uint4 vreg = *(const uint4*)(gV + kn);

        const uint4* Kl = Klds[buf];
        const uint2* Vl = (const uint2*)Vlds[buf];

        bf16x8 kf[2][2];
        #pragma unroll
        for (int t = 0; t < 2; ++t)
            #pragma unroll
            for (int c = 0; c < 2; ++c) {
                union { uint4 u; bf16x8 v; } cv;
                cv.u = Kl[(16 * t + col) * 8 + ((quad + 4 * c) ^ (col & 7))];
                kf[t][c] = cv.v;
            }
        // V^T A-fragments: vfrag[dt][t] = Vt[d=dt*16+col][key=16t+4quad+j]
        bf16x4 vfrag[4][2];
        #pragma unroll
        for (int dt = 0; dt < 4; ++dt)
            #pragma unroll
            for (int t = 0; t < 2; ++t) {
                const int slot = (dt * 8 + ch) * 8 + ((c1 * 4 + 2 * t + qh) ^ ch);
                union { uint2 u; bf16x4 v; } cv;
                cv.u = Vl[slot * 2 + ql];
                vfrag[dt][t] = cv.v;
            }

        #pragma unroll
        for (int s = 0; s < 2; ++s) {
            bf16x4 pw[2];
            #pragma unroll
            for (int t = 0; t < 2; ++t) {
                floatx4 sc = MFMA32(kf[t][1], aq[s][1], MFMA32(kf[t][0], aq[s][0], zf));
                const float p0 = __builtin_amdgcn_exp2f(sc[0]);
                const float p1 = __builtin_amdgcn_exp2f(sc[1]);
                const float p2 = __builtin_amdgcn_exp2f(sc[2]);
                const float p3 = __builtin_amdgcn_exp2f(sc[3]);
                lsum[s] += (p0 + p1) + (p2 + p3);
                union { bf16 e[4]; bf16x4 v; } pk;
                pk.e[0] = (bf16)p0; pk.e[1] = (bf16)p1;
                pk.e[2] = (bf16)p2; pk.e[3] = (bf16)p3;
                pw[t] = pk.v;
            }
            #pragma unroll
            for (int dt = 0; dt < 4; ++dt) {
                o[s][dt] = MFMA16(vfrag[dt][0], pw[0], o[s][dt]);
                o[s][dt] = MFMA16(vfrag[dt][1], pw[1], o[s][dt]);
            }
        }

        Klds[buf ^ 1][tid] = kreg;
        Vlds[buf ^ 1][tid] = vreg;
        __syncthreads();
        buf ^= 1;
    }

    // l reduction: keys split across quads only -> 2 shuffles per q-set
    float inv[2];
    #pragma unroll
    for (int s = 0; s < 2; ++s) {
        float v = lsum[s];
        v += __shfl_xor(v, 16, 64);
        v += __shfl_xor(v, 32, 64);
        inv[s] = 1.0f / v;
    }

    const int b = bh >> 3;
    const int h = bh & 7;
    #pragma unroll
    for (int s = 0; s < 2; ++s)
        #pragma unroll
        for (int dt = 0; dt < 4; ++dt) {
            union { bf16 e[4]; uint2 u; } pk;
            #pragma unroll
            for (int r = 0; r < 4; ++r) pk.e[r] = (bf16)(o[s][dt][r] * inv[s]);
            const size_t row = (size_t)b * 4096 + q0 + 16 * s + col;
            *(uint2*)(att + row * 512 + h * 64 + 16 * dt + 4 * quad) = pk.u;
        }
}

// ---------------------------------------------------------------------------
// Kernel 4: output projection GEMM. out[8192][512] fp32 = att @ Wto^T + bo.
// ---------------------------------------------------------------------------
__global__ __launch_bounds__(256) void k_oproj(
    const bf16* __restrict__ att, const bf16* __restrict__ Wto,
    const float* __restrict__ bo, float* __restrict__ out)
{
    __shared__ uint4 Al[2][512];
    __shared__ uint4 Bl[2][512];

    const int tid  = threadIdx.x;
    const int w    = tid >> 6;
    const int lane = tid & 63;
    const int col  = lane & 15;
    const int quad = lane >> 4;
    const int m0 = blockIdx.x * 128;
    const int n0 = blockIdx.y * 128;

    const bf16* gA0 = att + (size_t)(m0 + (tid >> 2)) * 512 + (tid & 3) * 8;
    const bf16* gA1 = gA0 + 64 * 512;
    const bf16* gB0 = Wto + (size_t)(n0 + (tid >> 2)) * 512 + (tid & 3) * 8;
    const bf16* gB1 = gB0 + 64 * 512;

    const floatx4 zf = {0.f, 0.f, 0.f, 0.f};
    floatx4 acc[4][4];
    #pragma unroll
    for (int a = 0; a < 4; ++a)
        #pragma unroll
        for (int b = 0; b < 4; ++b) acc[a][b] = zf;

    Al[0][tid]       = *(const uint4*)gA0;
    Al[0][tid + 256] = *(const uint4*)gA1;
    Bl[0][tid]       = *(const uint4*)gB0;
    Bl[0][tid + 256] = *(const uint4*)gB1;
    __syncthreads();

    const int mb = (w & 1) * 64;
    const int nb = (w >> 1) * 64;

    int buf = 0;
    for (int kk = 0; kk < 16; ++kk) {
        const int kn = ((kk + 1) & 15) * 32;
        const uint4 pa0 = *(const uint4*)(gA0 + kn);
        const uint4 pa1 = *(const uint4*)(gA1 + kn);
        const uint4 pb0 = *(const uint4*)(gB0 + kn);
        const uint4 pb1 = *(const uint4*)(gB1 + kn);

        const uint4* A4 = Al[buf];
        const uint4* B4 = Bl[buf];
        bf16x8 af[4], bfr[4];
        #pragma unroll
        for (int t = 0; t < 4; ++t) {
            union { uint4 u; bf16x8 v; } ca, cb;
            ca.u = A4[(mb + 16 * t + col) * 4 + quad];
            cb.u = B4[(nb + 16 * t + col) * 4 + quad];
            af[t] = ca.v;
            bfr[t] = cb.v;
        }
        #pragma unroll
        for (int tm = 0; tm < 4; ++tm)
            #pragma unroll
            for (int tn = 0; tn < 4; ++tn)
                acc[tm][tn] = MFMA32(af[tm], bfr[tn], acc[tm][tn]);

        Al[buf ^ 1][tid]       = pa0;
        Al[buf ^ 1][tid + 256] = pa1;
        Bl[buf ^ 1][tid]       = pb0;
        Bl[buf ^ 1][tid + 256] = pb1;
        __syncthreads();
        buf ^= 1;
    }

    #pragma unroll
    for (int tn = 0; tn < 4; ++tn) {
        const int n = n0 + nb + 16 * tn + col;
        const float bb = bo[n];
        #pragma unroll
        for (int tm = 0; tm < 4; ++tm)
            #pragma unroll
            for (int r = 0; r < 4; ++r) {
                const int m = m0 + mb + 16 * tm + quad * 4 + r;
                out[(size_t)m * 512 + n] = acc[tm][tn][r] + bb;
            }
    }
}

// ---------------------------------------------------------------------------
extern "C" void kernel_launch(void* const* d_in, const int* in_sizes, int n_in,
                              void* d_out, int out_size, void* d_ws, size_t ws_size,
                              hipStream_t stream)
{
    const float* X  = (const float*)d_in[0];
    const float* Wq = (const float*)d_in[1];
    const float* bq = (const float*)d_in[2];
    const float* Wk = (const float*)d_in[3];
    const float* bk = (const float*)d_in[4];
    const float* Wv = (const float*)d_in[5];
    const float* bv = (const float*)d_in[6];
    const float* Wo = (const float*)d_in[7];
    const float* bo = (const float*)d_in[8];

    // workspace (bf16 elements): Wcat(3) + Wto + Q + K + Vt + att = 34.1 MB
    bf16* Wtq = (bf16*)d_ws;                   // rows 0..511 of Wcat
    bf16* Wtk = Wtq + 512 * 512;               // rows 512..1023
    bf16* Wtv = Wtk + 512 * 512;               // rows 1024..1535
    bf16* Wto = Wtv + 512 * 512;
    bf16* Qs  = Wto + 512 * 512;               // [16][4096][64]
    bf16* Ks  = Qs + (size_t)16 * 4096 * 64;   // [16][4096][64]
    bf16* Vt  = Ks + (size_t)16 * 4096 * 64;   // [16][64][4096]
    bf16* att = Vt + (size_t)16 * 4096 * 64;   // [8192][512]

    bf16* Xb  = (bf16*)d_out;                  // scratch; consumed by k_qkv,
                                               // d_out rewritten only by k_oproj

    k_transpose<<<dim3(16, 16, 4), 256, 0, stream>>>(Wq, Wk, Wv, Wo, Wtq, Wtk, Wtv, Wto);
    k_cvtx<<<2048, 256, 0, stream>>>(X, Xb);
    k_qkv<<<dim3(64, 12), 256, 0, stream>>>(Xb, Wtq, bq, bk, bv, Qs, Ks, Vt);
    k_attn<<<512, 256, 0, stream>>>(Qs, Ks, Vt, att);
    k_oproj<<<dim3(64, 4), 256, 0, stream>>>(att, Wto, bo, (float*)d_out);
}